// Round 12
// baseline (213.629 us; speedup 1.0000x reference)
//
#include <hip/hip_runtime.h>
#include <hip/hip_bf16.h>

// EncoderLayer: B=2, S=2048, D_MODEL=512, H=8, D_FF=2048
// Round 26: r25 landed (199.9us, best; GEMM conflict fix verified).
// Remaining measured defect: attn carries 2.62M conflict cycles/dispatch
// (~10% of its runtime). Bank analysis at pb[72] (36dw = 4 banks/row):
// the 32 scalar pb softmax stores/thread/iter hit only 16 banks = 4-way.
// Fix = r15-validated pb pad 68 (34dw = 2 banks/row): stores spread all
// 32 banks (2 lanes/bank = free), reads stay at floor. smem 74240->72192.
// Everything else byte-identical to r25.
// ws (MiB): q[0,4)->attn_out; k[4,8)->x1; v[8,12)->ffacc; ctx[12,16);
//   xb[16,20) (dead after Wo); Vt[20,24) (dead after attn);
//   ffmid[16,32) after LN1. Peak 32 MiB.
// d_out first 6MB = transposed bf16 weights (LN2 overwrites at end).

#define D_MODEL 512
#define N_HEADS 8
#define D_K 64
#define D_FF 2048
#define BATCH 2
#define SEQ 2048
#define NROWS (BATCH * SEQ)

typedef __hip_bfloat16 bf16;
typedef __attribute__((ext_vector_type(8))) short bf16x8;
typedef __attribute__((ext_vector_type(4))) short bf16x4;
typedef __attribute__((ext_vector_type(4))) float f32x4;

__device__ __forceinline__ unsigned short f2b(float f) {
  union { bf16 b; unsigned short u; } cv;
  cv.b = __float2bfloat16(f);
  return cv.u;
}
__device__ __forceinline__ float b2f(unsigned short u) {
  return __uint_as_float(((unsigned int)u) << 16);
}
__device__ __forceinline__ float toF(const bf16 x) { return __bfloat162float(x); }
__device__ __forceinline__ float toF(const float x) { return x; }
__device__ __forceinline__ void storeC(float* p, float v) { *p = v; }
__device__ __forceinline__ void storeC(bf16* p, float v) {
  *p = __float2bfloat16(v);
}

__device__ __forceinline__ void ld8f(const float* p, float* v) {
  const float4 a = *(const float4*)p;
  const float4 b = *(const float4*)(p + 4);
  v[0] = a.x; v[1] = a.y; v[2] = a.z; v[3] = a.w;
  v[4] = b.x; v[5] = b.y; v[6] = b.z; v[7] = b.w;
}
__device__ __forceinline__ void ld8f(const bf16* p, float* v) {
  const bf16x8 u = *(const bf16x8*)p;
#pragma unroll
  for (int i = 0; i < 8; ++i) v[i] = b2f((unsigned short)u[i]);
}
__device__ __forceinline__ void st8f(float* p, const float* v) {
  *(float4*)p = make_float4(v[0], v[1], v[2], v[3]);
  *(float4*)(p + 4) = make_float4(v[4], v[5], v[6], v[7]);
}
__device__ __forceinline__ void st8f(bf16* p, const float* v) {
  bf16x8 u;
#pragma unroll
  for (int i = 0; i < 8; ++i) u[i] = (short)f2b(v[i]);
  *(bf16x8*)p = u;
}

// Wt element offsets inside the d_out scratch region
#define WT_Q 0
#define WT_K 262144
#define WT_V 524288
#define WT_O 786432
#define WT_1 1048576
#define WT_2 2097152

// ---------------------------------------------------------------------------
// prep: z<6: W[R][Cn] fp32 -> Wt[Cn][R] bf16 (transposed). z=6: x -> bf16.
// ---------------------------------------------------------------------------
__global__ __launch_bounds__(256) void prep_kernel(
    const float* __restrict__ Wq, const float* __restrict__ Wk,
    const float* __restrict__ Wv, const float* __restrict__ Wo,
    const float* __restrict__ W1, const float* __restrict__ W2,
    bf16* __restrict__ outw, const float* __restrict__ x,
    bf16* __restrict__ xb) {
  const int z = blockIdx.z;
  const int t = threadIdx.x;

  if (z == 6) {  // xconv
    const size_t base =
        ((size_t)(blockIdx.y * 32 + blockIdx.x) * 2048) + (size_t)t * 8;
    float v[8];
    ld8f(x + base, v);
    st8f(xb + base, v);
    return;
  }

  const float* W;
  int R, Cn;
  size_t off;
  if (z == 0)      { W = Wq; R = 512;  Cn = 512;  off = WT_Q; }
  else if (z == 1) { W = Wk; R = 512;  Cn = 512;  off = WT_K; }
  else if (z == 2) { W = Wv; R = 512;  Cn = 512;  off = WT_V; }
  else if (z == 3) { W = Wo; R = 512;  Cn = 512;  off = WT_O; }
  else if (z == 4) { W = W1; R = 512;  Cn = 2048; off = WT_1; }
  else             { W = W2; R = 2048; Cn = 512;  off = WT_2; }
  const int c0 = blockIdx.x * 64;
  const int r0 = blockIdx.y * 64;
  if (c0 >= Cn || r0 >= R) return;

  __shared__ short tile[64][72];  // [c][r]
  {
    const int r = t >> 2, cg = (t & 3) * 16;
    const float* src = &W[(size_t)(r0 + r) * Cn + c0 + cg];
#pragma unroll
    for (int i = 0; i < 4; ++i) {
      const float4 v = *(const float4*)(src + 4 * i);
      tile[cg + 4 * i + 0][r] = (short)f2b(v.x);
      tile[cg + 4 * i + 1][r] = (short)f2b(v.y);
      tile[cg + 4 * i + 2][r] = (short)f2b(v.z);
      tile[cg + 4 * i + 3][r] = (short)f2b(v.w);
    }
  }
  __syncthreads();
  {
    const int c = t >> 2, rg = (t & 3) * 16;
    short* dst = (short*)outw + off + (size_t)(c0 + c) * R + r0 + rg;
    *(bf16x8*)dst = *(const bf16x8*)&tile[c][rg];
    *(bf16x8*)(dst + 8) = *(const bf16x8*)&tile[c][rg + 8];
  }
}

// ---------------------------------------------------------------------------
// gemm_bf16<BM,BN,RELU,RESID,TRV>: C = A @ Wt^T + bias (+ R resid, ReLU).
// A[row][k] bf16 (lda), Wt[n][k] bf16 (ldk). BK=64, block=256 (4 waves).
// r20 register-prefetch staging; r25: linear [.][64] LDS with both-sides
// XOR swizzle col^=(row&7)*8 (shorts) on ds_write commits and b128 frag
// reads -> all accesses at the b128 bank floor. TRV: blockIdx.z==2 writes
// C transposed into Vt[(b*8+h)*64+d][k]. Grid (Nview/BN, M/BM, NZ).
// ---------------------------------------------------------------------------
template <int BM, int BN, bool RELU, bool RESID, bool TRV>
__global__ __launch_bounds__(256) void gemm_bf16_kernel(
    const bf16* __restrict__ A, int lda,
    const bf16* __restrict__ Wt0, const bf16* __restrict__ Wt1,
    const bf16* __restrict__ Wt2, int ldk,
    const float* __restrict__ b0, const float* __restrict__ b1,
    const float* __restrict__ b2,
    bf16* __restrict__ C0, bf16* __restrict__ C1, bf16* __restrict__ C2,
    int ldc, int K, const bf16* __restrict__ R) {
  const bf16* Wt = (blockIdx.z == 0) ? Wt0 : (blockIdx.z == 1 ? Wt1 : Wt2);
  const float* bias = (blockIdx.z == 0) ? b0 : (blockIdx.z == 1 ? b1 : b2);
  bf16* C = (blockIdx.z == 0) ? C0 : (blockIdx.z == 1 ? C1 : C2);

  constexpr int WX = BN / 64;        // waves along N
  constexpr int WY = 4 / WX;         // waves along M
  constexpr int RG = BM / (16 * WY); // 16-row groups per wave
  constexpr int NA = BM / 32;        // A 16B-slots per thread
  constexpr int NW = BN / 32;        // W 16B-slots per thread

  __shared__ __align__(16) short as_[BM][64];
  __shared__ __align__(16) short bs[BN][64];

  const int rowBase = blockIdx.y * BM;
  const int colBase = blockIdx.x * BN;
  const int t = threadIdx.x;
  const int wave = t >> 6;
  const int lane = t & 63;
  const int quad = lane >> 4;
  const int l15 = lane & 15;
  const int wy = wave / WX;
  const int wx = wave % WX;

  const int arow = (NA == 2) ? (t >> 2) : (t >> 1);
  const int akc = (NA == 2) ? ((t & 3) * 16) : ((t & 1) * 32);
  const int wrow = (NW == 2) ? (t >> 2) : (t >> 1);
  const int wkc = (NW == 2) ? ((t & 3) * 16) : ((t & 1) * 32);

  const short* Abase = (const short*)A + (size_t)(rowBase + arow) * lda + akc;
  const short* Wbase = (const short*)Wt + (size_t)(colBase + wrow) * ldk + wkc;

  bf16x8 areg[NA], wreg[NW];
#pragma unroll
  for (int i = 0; i < NA; ++i) areg[i] = *(const bf16x8*)(Abase + 8 * i);
#pragma unroll
  for (int i = 0; i < NW; ++i) wreg[i] = *(const bf16x8*)(Wbase + 8 * i);

  f32x4 acc[RG][4];
#pragma unroll
  for (int i = 0; i < RG; ++i)
#pragma unroll
    for (int nt = 0; nt < 4; ++nt) acc[i][nt] = (f32x4){0.f, 0.f, 0.f, 0.f};

  const int aswz = (arow & 7) * 8;
  const int wswz = (wrow & 7) * 8;
  const int rswz = (l15 & 7) * 8;

  for (int k0 = 0; k0 < K; k0 += 64) {
    // commit prefetched tile (swizzled cols)
#pragma unroll
    for (int i = 0; i < NA; ++i)
      *(bf16x8*)&as_[arow][(akc + 8 * i) ^ aswz] = areg[i];
#pragma unroll
    for (int i = 0; i < NW; ++i)
      *(bf16x8*)&bs[wrow][(wkc + 8 * i) ^ wswz] = wreg[i];

    // issue next tile's loads
    if (k0 + 64 < K) {
#pragma unroll
      for (int i = 0; i < NA; ++i)
        areg[i] = *(const bf16x8*)(Abase + k0 + 64 + 8 * i);
#pragma unroll
      for (int i = 0; i < NW; ++i)
        wreg[i] = *(const bf16x8*)(Wbase + k0 + 64 + 8 * i);
    }
    __syncthreads();

#pragma unroll
    for (int kc = 0; kc < 2; ++kc) {
      bf16x8 af[RG];
#pragma unroll
      for (int i = 0; i < RG; ++i)
        af[i] = *(const bf16x8*)
            &as_[wy * (16 * RG) + i * 16 + l15][(quad * 8 + kc * 32) ^ rswz];
#pragma unroll
      for (int nt = 0; nt < 4; ++nt) {
        const bf16x8 bfr = *(const bf16x8*)
            &bs[wx * 64 + nt * 16 + l15][(quad * 8 + kc * 32) ^ rswz];
#pragma unroll
        for (int i = 0; i < RG; ++i)
          acc[i][nt] = __builtin_amdgcn_mfma_f32_16x16x32_bf16(
              af[i], bfr, acc[i][nt], 0, 0, 0);
      }
    }
    __syncthreads();
  }

  if (TRV && blockIdx.z == 2) {
    // transposed V write: Vt[(b*8+h)*64 + d][k], 4 bf16 (8B) per store
#pragma unroll
    for (int i = 0; i < RG; ++i)
#pragma unroll
      for (int nt = 0; nt < 4; ++nt) {
        const int col = colBase + wx * 64 + nt * 16 + l15;
        const int h_ = col >> 6, d_ = col & 63;
        const int row0 = rowBase + wy * (16 * RG) + i * 16 + quad * 4;
        const int b_ = row0 >> 11, k0_ = row0 & 2047;
        const float bia = bias[col];
        bf16x4 u;
#pragma unroll
        for (int r = 0; r < 4; ++r) u[r] = (short)f2b(acc[i][nt][r] + bia);
        *(bf16x4*)((unsigned short*)C +
                   ((size_t)((b_ * 8 + h_) * 64 + d_)) * 2048 + k0_) = u;
      }
    return;
  }

#pragma unroll
  for (int i = 0; i < RG; ++i)
#pragma unroll
    for (int nt = 0; nt < 4; ++nt) {
      const int col = colBase + wx * 64 + nt * 16 + l15;
#pragma unroll
      for (int r = 0; r < 4; ++r) {
        const int row = rowBase + wy * (16 * RG) + i * 16 + quad * 4 + r;
        float v = acc[i][nt][r] + bias[col];
        if (RESID) v += toF(R[(size_t)row * ldc + col]);
        if (RELU) v = fmaxf(v, 0.f);
        storeC(&C[(size_t)row * ldc + col], v);
      }
    }
}

// ---------------------------------------------------------------------------
// MFMA flash attention, RG=2 (r20 structure). grid (SEQ/128, B*H), block 512.
// V pre-transposed (Vt[(b*8+h)*64+d][k]) -> V staging = 2 b128 writes.
// r26: pb pad 72->68 shorts (34dw = 2 banks/row): the 32 scalar softmax
// stores/thread/iter go 4-way-conflict -> conflict-free (2 lanes/bank).
// smem 74240 -> 72192.
// ---------------------------------------------------------------------------
__global__ __launch_bounds__(512) void attn_mfma_kernel(
    const bf16* __restrict__ Q, const bf16* __restrict__ Km,
    const bf16* __restrict__ Vt_g, const int* __restrict__ mask,
    bf16* __restrict__ ctx) {
  const int qt = blockIdx.x;
  const int bh = blockIdx.y;
  const int b = bh >> 3;
  const int h = bh & 7;
  const int t = threadIdx.x;
  const int wave = t >> 6;
  const int half = wave >> 2;
  const int wq = wave & 3;
  const int lane = t & 63;
  const int quad = lane >> 4;
  const int l15 = lane & 15;

  __shared__ __align__(16) char smem[72192];
  auto ks = (short(*)[64][72])(smem);           // 2*64*72*2 = 18432
  auto vt = (short(*)[64][72])(smem + 18432);   // 18432
  auto pb = (short(*)[32][68])(smem + 36864);   // 8*32*68*2 = 34816
  auto mk = (int(*)[64])(smem + 71680);         // 512
  auto mg = (float(*)[32][68])(smem);           // 69632, aliases ks/vt/pb

  bf16x8 qf[2][2];
#pragma unroll
  for (int rg = 0; rg < 2; ++rg) {
    const short* qg = (const short*)Q +
        (size_t)(b * SEQ + qt * 128 + wq * 32 + rg * 16 + l15) * D_MODEL +
        h * D_K + quad * 8;
    qf[rg][0] = *(const bf16x8*)qg;
    qf[rg][1] = *(const bf16x8*)(qg + 32);
  }

  f32x4 of[2][4];
#pragma unroll
  for (int rg = 0; rg < 2; ++rg)
#pragma unroll
    for (int nt = 0; nt < 4; ++nt) of[rg][nt] = (f32x4){0.f, 0.f, 0.f, 0.f};
  float l_acc[2][4] = {{0.f, 0.f, 0.f, 0.f}, {0.f, 0.f, 0.f, 0.f}};

  const int hs = t >> 8;
  const int tt = t & 255;
  const int kr = tt >> 2, kc0 = (tt & 3) * 16;

  // Vt row for this thread: d = kr; k runs along columns (contiguous)
  const short* VtRow = (const short*)Vt_g + (size_t)(bh * 64 + kr) * 2048;

  bf16x8 kv0, kv1, vv0, vv1;
  int mv = 1;
  {
    const int keyRow = (hs * 16 + 0) * 64;
    const short* kg = (const short*)Km +
        (size_t)(b * SEQ + keyRow + kr) * D_MODEL + h * D_K + kc0;
    kv0 = *(const bf16x8*)kg;
    kv1 = *(const bf16x8*)(kg + 8);
    const short* vg = VtRow + keyRow + kc0;
    vv0 = *(const bf16x8*)vg;
    vv1 = *(const bf16x8*)(vg + 8);
    if (tt < 64) mv = mask[b * SEQ + keyRow + tt];
  }

  for (int kt = 0; kt < 16; ++kt) {
    *(bf16x8*)&ks[hs][kr][kc0] = kv0;
    *(bf16x8*)&ks[hs][kr][kc0 + 8] = kv1;
    *(bf16x8*)&vt[hs][kr][kc0] = vv0;
    *(bf16x8*)&vt[hs][kr][kc0 + 8] = vv1;
    if (tt < 64) mk[hs][tt] = mv;

    if (kt + 1 < 16) {
      const int keyRow = (hs * 16 + kt + 1) * 64;
      const short* kg = (const short*)Km +
          (size_t)(b * SEQ + keyRow + kr) * D_MODEL + h * D_K + kc0;
      kv0 = *(const bf16x8*)kg;
      kv1 = *(const bf16x8*)(kg + 8);
      const short* vg = VtRow + keyRow + kc0;
      vv0 = *(const bf16x8*)vg;
      vv1 = *(const bf16x8*)(vg + 8);
      if (tt < 64) mv = mask[b * SEQ + keyRow + tt];
    }
    __syncthreads();

    f32x4 sf[2][4];
#pragma unroll
    for (int nt = 0; nt < 4; ++nt) {
      const bf16x8 kf0 = *(const bf16x8*)&ks[half][l15 + 16 * nt][quad * 8];
      const bf16x8 kf1 =
          *(const bf16x8*)&ks[half][l15 + 16 * nt][quad * 8 + 32];
#pragma unroll
      for (int rg = 0; rg < 2; ++rg) {
        f32x4 acc = (f32x4){0.f, 0.f, 0.f, 0.f};
        acc = __builtin_amdgcn_mfma_f32_16x16x32_bf16(qf[rg][0], kf0, acc, 0, 0, 0);
        acc = __builtin_amdgcn_mfma_f32_16x16x32_bf16(qf[rg][1], kf1, acc, 0, 0, 0);
        sf[rg][nt] = acc;
      }
    }

#pragma unroll
    for (int nt = 0; nt < 4; ++nt) {
      const bool dead = (mk[half][l15 + 16 * nt] == 0);
#pragma unroll
      for (int rg = 0; rg < 2; ++rg)
#pragma unroll
        for (int r = 0; r < 4; ++r) {
          float p = __expf(fmaf(sf[rg][nt][r], 0.125f, -8.f));
          if (dead) p = 0.f;
          l_acc[rg][r] += p;
          pb[wave][rg * 16 + quad * 4 + r][l15 + 16 * nt] = (short)f2b(p);
        }
    }

#pragma unroll
    for (int kc = 0; kc < 2; ++kc) {
      bf16x8 pf[2];
#pragma unroll
      for (int rg = 0; rg < 2; ++rg)
        pf[rg] = *(const bf16x8*)&pb[wave][rg * 16 + l15][kc * 32 + quad * 8];
#pragma unroll
      for (int nt = 0; nt < 4; ++nt) {
        const bf16x8 vf =
            *(const bf16x8*)&vt[half][l15 + 16 * nt][kc * 32 + quad * 8];
#pragma unroll
        for (int rg = 0; rg < 2; ++rg)
          of[rg][nt] = __builtin_amdgcn_mfma_f32_16x16x32_bf16(
              pf[rg], vf, of[rg][nt], 0, 0, 0);
      }
    }
    __syncthreads();
  }

#pragma unroll
  for (int xm = 1; xm < 16; xm <<= 1)
#pragma unroll
    for (int rg = 0; rg < 2; ++rg)
#pragma unroll
      for (int r = 0; r < 4; ++r)
        l_acc[rg][r] += __shfl_xor(l_acc[rg][r], xm, 64);

#pragma unroll
  for (int rg = 0; rg < 2; ++rg)
#pragma unroll
    for (int nt = 0; nt < 4; ++nt)
#pragma unroll
      for (int r = 0; r < 4; ++r)
        mg[wave][rg * 16 + quad * 4 + r][l15 + 16 * nt] = of[rg][nt][r];
  if (l15 == 0) {
#pragma unroll
    for (int rg = 0; rg < 2; ++rg)
#pragma unroll
      for (int r = 0; r < 4; ++r)
        mg[wave][rg * 16 + quad * 4 + r][64] = l_acc[rg][r];
  }
  __syncthreads();

  if (wave < 4) {
    const int pw = wave + 4;
#pragma unroll
    for (int rg = 0; rg < 2; ++rg)
#pragma unroll
      for (int r = 0; r < 4; ++r) {
        const int qrow = rg * 16 + quad * 4 + r;
        const float inv = 1.f / (l_acc[rg][r] + mg[pw][qrow][64]);
        const int row = qt * 128 + wave * 32 + qrow;
        bf16* cp = ctx + (size_t)(b * SEQ + row) * D_MODEL + h * D_K;
#pragma unroll
        for (int nt = 0; nt < 4; ++nt)
          cp[l15 + 16 * nt] = __float2bfloat16(
              (of[rg][nt][r] + mg[pw][qrow][l15 + 16 * nt]) * inv);
      }
  }
}

// ---------------------------------------------------------------------------
// Wave-per-row LayerNorm (single input): out = LN(base)*g+beta.
// block 256 = 4 rows, grid NROWS/4. Shfl butterfly only.
// ---------------------------------------------------------------------------
template <typename BT, typename OT>
__global__ __launch_bounds__(256) void ln_kernel(
    const BT* __restrict__ base, const float* __restrict__ g,
    const float* __restrict__ beta, OT* __restrict__ out) {
  const int wave = threadIdx.x >> 6;
  const int lane = threadIdx.x & 63;
  const int row = blockIdx.x * 4 + wave;
  const size_t rb = (size_t)row * D_MODEL + lane * 8;

  float v[8];
  ld8f(base + rb, v);

  float s = 0.f;
#pragma unroll
  for (int i = 0; i < 8; ++i) s += v[i];
#pragma unroll
  for (int xm = 1; xm < 64; xm <<= 1) s += __shfl_xor(s, xm, 64);
  const float mu = s * (1.f / (float)D_MODEL);

  float q = 0.f;
#pragma unroll
  for (int i = 0; i < 8; ++i) {
    v[i] -= mu;
    q += v[i] * v[i];
  }
#pragma unroll
  for (int xm = 1; xm < 64; xm <<= 1) q += __shfl_xor(q, xm, 64);
  const float rs = rsqrtf(q * (1.f / (float)D_MODEL) + 1e-5f);

  float gv[8], bv[8];
  ld8f(g + lane * 8, gv);
  ld8f(beta + lane * 8, bv);
#pragma unroll
  for (int i = 0; i < 8; ++i) v[i] = v[i] * rs * gv[i] + bv[i];
  st8f(out + rb, v);
}

// ---------------------------------------------------------------------------
extern "C" void kernel_launch(void* const* d_in, const int* in_sizes, int n_in,
                              void* d_out, int out_size, void* d_ws, size_t ws_size,
                              hipStream_t stream) {
  const float* x     = (const float*)d_in[0];
  const int*   mask  = (const int*)d_in[1];
  const float* Wq    = (const float*)d_in[2];
  const float* bq    = (const float*)d_in[3];
  const float* Wk    = (const float*)d_in[4];
  const float* bk    = (const float*)d_in[5];
  const float* Wv    = (const float*)d_in[6];
  const float* bv    = (const float*)d_in[7];
  const float* Wo    = (const float*)d_in[8];
  const float* bo    = (const float*)d_in[9];
  const float* W1    = (const float*)d_in[10];
  const float* b1    = (const float*)d_in[11];
  const float* W2    = (const float*)d_in[12];
  const float* b2    = (const float*)d_in[13];
  const float* g1    = (const float*)d_in[14];
  const float* beta1 = (const float*)d_in[15];
  const float* g2    = (const float*)d_in[16];
  const float* beta2 = (const float*)d_in[17];
  float* out = (float*)d_out;

  char* ws = (char*)d_ws;
  const size_t MB4 = (size_t)NROWS * D_MODEL * sizeof(bf16);  // 4 MiB
  bf16* q        = (bf16*)(ws + 0 * MB4);
  bf16* kbuf     = (bf16*)(ws + 1 * MB4);
  bf16* vbuf     = (bf16*)(ws + 2 * MB4);  // ffacc later
  bf16* ctx      = (bf16*)(ws + 3 * MB4);
  bf16* xb       = (bf16*)(ws + 4 * MB4);  // [16,20), dead after Wo
  bf16* vtbuf    = (bf16*)(ws + 5 * MB4);  // [20,24), Vt; dead after attn
  bf16* attn_out = q;                      // q dead after attention
  bf16* x1       = kbuf;                   // k dead after attention
  bf16* ffacc    = vbuf;                   // v dead after attention
  bf16* ffmid    = (bf16*)(ws + 4 * MB4);  // [16,32), xb/Vt dead by FF1

  bf16* wt = (bf16*)d_out;  // 6MB transposed bf16 weights (LN2 overwrites)

  const dim3 blk(256);

  // prep: weights -> bf16 transposed; x -> bf16 (z=6)
  prep_kernel<<<dim3(32, 32, 7), blk, 0, stream>>>(Wq, Wk, Wv, Wo, W1, W2, wt,
                                                   x, xb);

  // QKV fused, 64x128 tile: 768 blocks = 3/CU. z=2 (V) writes transposed.
  gemm_bf16_kernel<64, 128, false, false, true>
      <<<dim3(D_MODEL / 128, NROWS / 64, 3), blk, 0, stream>>>(
          xb, D_MODEL, wt + WT_Q, wt + WT_K, wt + WT_V, D_MODEL,
          bq, bk, bv, q, kbuf, vtbuf, D_MODEL, D_MODEL, nullptr);

  // attention (RG=2: 128 q rows per block; V pre-transposed)
  attn_mfma_kernel<<<dim3(SEQ / 128, BATCH * N_HEADS), dim3(512), 0, stream>>>(
      q, kbuf, vtbuf, mask, ctx);

  // Wo projection + residual (xb), 64x64 tile: 512 blocks = 2/CU
  gemm_bf16_kernel<64, 64, false, true, false>
      <<<dim3(D_MODEL / 64, NROWS / 64, 1), blk, 0, stream>>>(
          ctx, D_MODEL, wt + WT_O, wt + WT_O, wt + WT_O, D_MODEL,
          bo, bo, bo, attn_out, attn_out, attn_out, D_MODEL, D_MODEL, xb);

  // LN1: x1 = LN(attn_out) -> bf16
  ln_kernel<bf16, bf16><<<NROWS / 4, blk, 0, stream>>>(attn_out, g1, beta1, x1);

  // FF1, 64x128 tile: ffmid = relu(x1 @ W1 + b1), 1024 blocks = 4/CU
  gemm_bf16_kernel<64, 128, true, false, false>
      <<<dim3(D_FF / 128, NROWS / 64, 1), blk, 0, stream>>>(
          x1, D_MODEL, wt + WT_1, wt + WT_1, wt + WT_1, D_MODEL,
          b1, b1, b1, ffmid, ffmid, ffmid, D_FF, D_MODEL, nullptr);

  // FF2 (K=2048) + residual (x1), 64x64 tile: 512 blocks = 2/CU
  gemm_bf16_kernel<64, 64, false, true, false>
      <<<dim3(D_MODEL / 64, NROWS / 64, 1), blk, 0, stream>>>(
          ffmid, D_FF, wt + WT_2, wt + WT_2, wt + WT_2, D_FF,
          b2, b2, b2, ffacc, ffacc, ffacc, D_MODEL, D_FF, x1);

  // LN2 -> fp32 output (overwrites wt scratch)
  ln_kernel<bf16, float><<<NROWS / 4, blk, 0, stream>>>(ffacc, g2, beta2, out);
}

// Round 13
// 200.473 us; speedup vs baseline: 1.0656x; 1.0656x over previous
//
#include <hip/hip_runtime.h>
#include <hip/hip_bf16.h>

// EncoderLayer: B=2, S=2048, D_MODEL=512, H=8, D_FF=2048
// Round 27: REVERT r26 (pb pad 68 broke 16B alignment of pb rows ->
// ds_read_b128 splits; attn 44->59us, conflicts only -0.5M). Back to r25
// byte-for-byte (best, 199.9us). Lessons: LDS row strides for b128 access
// must stay multiples of 8 shorts; attn conflict counter is mostly b128
// floor accounting, not fixable stalls.
// Budget at 199.9: ~90us harness fills (fixed) + attn ~40 (LDS-pipe floor)
// + GEMM ~50 (K-loops ~43, L2-fill-traffic-bound) + prep/LN ~12.
// ws (MiB): q[0,4)->attn_out; k[4,8)->x1; v[8,12)->ffacc; ctx[12,16);
//   xb[16,20) (dead after Wo); Vt[20,24) (dead after attn);
//   ffmid[16,32) after LN1. Peak 32 MiB.
// d_out first 6MB = transposed bf16 weights (LN2 overwrites at end).

#define D_MODEL 512
#define N_HEADS 8
#define D_K 64
#define D_FF 2048
#define BATCH 2
#define SEQ 2048
#define NROWS (BATCH * SEQ)

typedef __hip_bfloat16 bf16;
typedef __attribute__((ext_vector_type(8))) short bf16x8;
typedef __attribute__((ext_vector_type(4))) short bf16x4;
typedef __attribute__((ext_vector_type(4))) float f32x4;

__device__ __forceinline__ unsigned short f2b(float f) {
  union { bf16 b; unsigned short u; } cv;
  cv.b = __float2bfloat16(f);
  return cv.u;
}
__device__ __forceinline__ float b2f(unsigned short u) {
  return __uint_as_float(((unsigned int)u) << 16);
}
__device__ __forceinline__ float toF(const bf16 x) { return __bfloat162float(x); }
__device__ __forceinline__ float toF(const float x) { return x; }
__device__ __forceinline__ void storeC(float* p, float v) { *p = v; }
__device__ __forceinline__ void storeC(bf16* p, float v) {
  *p = __float2bfloat16(v);
}

__device__ __forceinline__ void ld8f(const float* p, float* v) {
  const float4 a = *(const float4*)p;
  const float4 b = *(const float4*)(p + 4);
  v[0] = a.x; v[1] = a.y; v[2] = a.z; v[3] = a.w;
  v[4] = b.x; v[5] = b.y; v[6] = b.z; v[7] = b.w;
}
__device__ __forceinline__ void ld8f(const bf16* p, float* v) {
  const bf16x8 u = *(const bf16x8*)p;
#pragma unroll
  for (int i = 0; i < 8; ++i) v[i] = b2f((unsigned short)u[i]);
}
__device__ __forceinline__ void st8f(float* p, const float* v) {
  *(float4*)p = make_float4(v[0], v[1], v[2], v[3]);
  *(float4*)(p + 4) = make_float4(v[4], v[5], v[6], v[7]);
}
__device__ __forceinline__ void st8f(bf16* p, const float* v) {
  bf16x8 u;
#pragma unroll
  for (int i = 0; i < 8; ++i) u[i] = (short)f2b(v[i]);
  *(bf16x8*)p = u;
}

// Wt element offsets inside the d_out scratch region
#define WT_Q 0
#define WT_K 262144
#define WT_V 524288
#define WT_O 786432
#define WT_1 1048576
#define WT_2 2097152

// ---------------------------------------------------------------------------
// prep: z<6: W[R][Cn] fp32 -> Wt[Cn][R] bf16 (transposed). z=6: x -> bf16.
// ---------------------------------------------------------------------------
__global__ __launch_bounds__(256) void prep_kernel(
    const float* __restrict__ Wq, const float* __restrict__ Wk,
    const float* __restrict__ Wv, const float* __restrict__ Wo,
    const float* __restrict__ W1, const float* __restrict__ W2,
    bf16* __restrict__ outw, const float* __restrict__ x,
    bf16* __restrict__ xb) {
  const int z = blockIdx.z;
  const int t = threadIdx.x;

  if (z == 6) {  // xconv
    const size_t base =
        ((size_t)(blockIdx.y * 32 + blockIdx.x) * 2048) + (size_t)t * 8;
    float v[8];
    ld8f(x + base, v);
    st8f(xb + base, v);
    return;
  }

  const float* W;
  int R, Cn;
  size_t off;
  if (z == 0)      { W = Wq; R = 512;  Cn = 512;  off = WT_Q; }
  else if (z == 1) { W = Wk; R = 512;  Cn = 512;  off = WT_K; }
  else if (z == 2) { W = Wv; R = 512;  Cn = 512;  off = WT_V; }
  else if (z == 3) { W = Wo; R = 512;  Cn = 512;  off = WT_O; }
  else if (z == 4) { W = W1; R = 512;  Cn = 2048; off = WT_1; }
  else             { W = W2; R = 2048; Cn = 512;  off = WT_2; }
  const int c0 = blockIdx.x * 64;
  const int r0 = blockIdx.y * 64;
  if (c0 >= Cn || r0 >= R) return;

  __shared__ short tile[64][72];  // [c][r]
  {
    const int r = t >> 2, cg = (t & 3) * 16;
    const float* src = &W[(size_t)(r0 + r) * Cn + c0 + cg];
#pragma unroll
    for (int i = 0; i < 4; ++i) {
      const float4 v = *(const float4*)(src + 4 * i);
      tile[cg + 4 * i + 0][r] = (short)f2b(v.x);
      tile[cg + 4 * i + 1][r] = (short)f2b(v.y);
      tile[cg + 4 * i + 2][r] = (short)f2b(v.z);
      tile[cg + 4 * i + 3][r] = (short)f2b(v.w);
    }
  }
  __syncthreads();
  {
    const int c = t >> 2, rg = (t & 3) * 16;
    short* dst = (short*)outw + off + (size_t)(c0 + c) * R + r0 + rg;
    *(bf16x8*)dst = *(const bf16x8*)&tile[c][rg];
    *(bf16x8*)(dst + 8) = *(const bf16x8*)&tile[c][rg + 8];
  }
}

// ---------------------------------------------------------------------------
// gemm_bf16<BM,BN,RELU,RESID,TRV>: C = A @ Wt^T + bias (+ R resid, ReLU).
// A[row][k] bf16 (lda), Wt[n][k] bf16 (ldk). BK=64, block=256 (4 waves).
// r20 register-prefetch staging; r25: linear [.][64] LDS with both-sides
// XOR swizzle col^=(row&7)*8 (shorts) on ds_write commits and b128 frag
// reads -> all accesses at the b128 bank floor. TRV: blockIdx.z==2 writes
// C transposed into Vt[(b*8+h)*64+d][k]. Grid (Nview/BN, M/BM, NZ).
// ---------------------------------------------------------------------------
template <int BM, int BN, bool RELU, bool RESID, bool TRV>
__global__ __launch_bounds__(256) void gemm_bf16_kernel(
    const bf16* __restrict__ A, int lda,
    const bf16* __restrict__ Wt0, const bf16* __restrict__ Wt1,
    const bf16* __restrict__ Wt2, int ldk,
    const float* __restrict__ b0, const float* __restrict__ b1,
    const float* __restrict__ b2,
    bf16* __restrict__ C0, bf16* __restrict__ C1, bf16* __restrict__ C2,
    int ldc, int K, const bf16* __restrict__ R) {
  const bf16* Wt = (blockIdx.z == 0) ? Wt0 : (blockIdx.z == 1 ? Wt1 : Wt2);
  const float* bias = (blockIdx.z == 0) ? b0 : (blockIdx.z == 1 ? b1 : b2);
  bf16* C = (blockIdx.z == 0) ? C0 : (blockIdx.z == 1 ? C1 : C2);

  constexpr int WX = BN / 64;        // waves along N
  constexpr int WY = 4 / WX;         // waves along M
  constexpr int RG = BM / (16 * WY); // 16-row groups per wave
  constexpr int NA = BM / 32;        // A 16B-slots per thread
  constexpr int NW = BN / 32;        // W 16B-slots per thread

  __shared__ __align__(16) short as_[BM][64];
  __shared__ __align__(16) short bs[BN][64];

  const int rowBase = blockIdx.y * BM;
  const int colBase = blockIdx.x * BN;
  const int t = threadIdx.x;
  const int wave = t >> 6;
  const int lane = t & 63;
  const int quad = lane >> 4;
  const int l15 = lane & 15;
  const int wy = wave / WX;
  const int wx = wave % WX;

  const int arow = (NA == 2) ? (t >> 2) : (t >> 1);
  const int akc = (NA == 2) ? ((t & 3) * 16) : ((t & 1) * 32);
  const int wrow = (NW == 2) ? (t >> 2) : (t >> 1);
  const int wkc = (NW == 2) ? ((t & 3) * 16) : ((t & 1) * 32);

  const short* Abase = (const short*)A + (size_t)(rowBase + arow) * lda + akc;
  const short* Wbase = (const short*)Wt + (size_t)(colBase + wrow) * ldk + wkc;

  bf16x8 areg[NA], wreg[NW];
#pragma unroll
  for (int i = 0; i < NA; ++i) areg[i] = *(const bf16x8*)(Abase + 8 * i);
#pragma unroll
  for (int i = 0; i < NW; ++i) wreg[i] = *(const bf16x8*)(Wbase + 8 * i);

  f32x4 acc[RG][4];
#pragma unroll
  for (int i = 0; i < RG; ++i)
#pragma unroll
    for (int nt = 0; nt < 4; ++nt) acc[i][nt] = (f32x4){0.f, 0.f, 0.f, 0.f};

  const int aswz = (arow & 7) * 8;
  const int wswz = (wrow & 7) * 8;
  const int rswz = (l15 & 7) * 8;

  for (int k0 = 0; k0 < K; k0 += 64) {
    // commit prefetched tile (swizzled cols)
#pragma unroll
    for (int i = 0; i < NA; ++i)
      *(bf16x8*)&as_[arow][(akc + 8 * i) ^ aswz] = areg[i];
#pragma unroll
    for (int i = 0; i < NW; ++i)
      *(bf16x8*)&bs[wrow][(wkc + 8 * i) ^ wswz] = wreg[i];

    // issue next tile's loads
    if (k0 + 64 < K) {
#pragma unroll
      for (int i = 0; i < NA; ++i)
        areg[i] = *(const bf16x8*)(Abase + k0 + 64 + 8 * i);
#pragma unroll
      for (int i = 0; i < NW; ++i)
        wreg[i] = *(const bf16x8*)(Wbase + k0 + 64 + 8 * i);
    }
    __syncthreads();

#pragma unroll
    for (int kc = 0; kc < 2; ++kc) {
      bf16x8 af[RG];
#pragma unroll
      for (int i = 0; i < RG; ++i)
        af[i] = *(const bf16x8*)
            &as_[wy * (16 * RG) + i * 16 + l15][(quad * 8 + kc * 32) ^ rswz];
#pragma unroll
      for (int nt = 0; nt < 4; ++nt) {
        const bf16x8 bfr = *(const bf16x8*)
            &bs[wx * 64 + nt * 16 + l15][(quad * 8 + kc * 32) ^ rswz];
#pragma unroll
        for (int i = 0; i < RG; ++i)
          acc[i][nt] = __builtin_amdgcn_mfma_f32_16x16x32_bf16(
              af[i], bfr, acc[i][nt], 0, 0, 0);
      }
    }
    __syncthreads();
  }

  if (TRV && blockIdx.z == 2) {
    // transposed V write: Vt[(b*8+h)*64 + d][k], 4 bf16 (8B) per store
#pragma unroll
    for (int i = 0; i < RG; ++i)
#pragma unroll
      for (int nt = 0; nt < 4; ++nt) {
        const int col = colBase + wx * 64 + nt * 16 + l15;
        const int h_ = col >> 6, d_ = col & 63;
        const int row0 = rowBase + wy * (16 * RG) + i * 16 + quad * 4;
        const int b_ = row0 >> 11, k0_ = row0 & 2047;
        const float bia = bias[col];
        bf16x4 u;
#pragma unroll
        for (int r = 0; r < 4; ++r) u[r] = (short)f2b(acc[i][nt][r] + bia);
        *(bf16x4*)((unsigned short*)C +
                   ((size_t)((b_ * 8 + h_) * 64 + d_)) * 2048 + k0_) = u;
      }
    return;
  }

#pragma unroll
  for (int i = 0; i < RG; ++i)
#pragma unroll
    for (int nt = 0; nt < 4; ++nt) {
      const int col = colBase + wx * 64 + nt * 16 + l15;
#pragma unroll
      for (int r = 0; r < 4; ++r) {
        const int row = rowBase + wy * (16 * RG) + i * 16 + quad * 4 + r;
        float v = acc[i][nt][r] + bias[col];
        if (RESID) v += toF(R[(size_t)row * ldc + col]);
        if (RELU) v = fmaxf(v, 0.f);
        storeC(&C[(size_t)row * ldc + col], v);
      }
    }
}

// ---------------------------------------------------------------------------
// MFMA flash attention, RG=2 (r20/r25 verbatim). grid (SEQ/128, B*H),
// block 512. V pre-transposed (Vt[(b*8+h)*64+d][k]) -> V staging = 2 b128
// writes. pb stride 72 (16B-aligned rows; r26's 68 broke b128 alignment).
// ---------------------------------------------------------------------------
__global__ __launch_bounds__(512) void attn_mfma_kernel(
    const bf16* __restrict__ Q, const bf16* __restrict__ Km,
    const bf16* __restrict__ Vt_g, const int* __restrict__ mask,
    bf16* __restrict__ ctx) {
  const int qt = blockIdx.x;
  const int bh = blockIdx.y;
  const int b = bh >> 3;
  const int h = bh & 7;
  const int t = threadIdx.x;
  const int wave = t >> 6;
  const int half = wave >> 2;
  const int wq = wave & 3;
  const int lane = t & 63;
  const int quad = lane >> 4;
  const int l15 = lane & 15;

  __shared__ __align__(16) char smem[74240];
  auto ks = (short(*)[64][72])(smem);
  auto vt = (short(*)[64][72])(smem + 18432);
  auto pb = (short(*)[32][72])(smem + 36864);
  auto mk = (int(*)[64])(smem + 73728);
  auto mg = (float(*)[32][68])(smem);  // aliases ks/vt/pb after final barrier

  bf16x8 qf[2][2];
#pragma unroll
  for (int rg = 0; rg < 2; ++rg) {
    const short* qg = (const short*)Q +
        (size_t)(b * SEQ + qt * 128 + wq * 32 + rg * 16 + l15) * D_MODEL +
        h * D_K + quad * 8;
    qf[rg][0] = *(const bf16x8*)qg;
    qf[rg][1] = *(const bf16x8*)(qg + 32);
  }

  f32x4 of[2][4];
#pragma unroll
  for (int rg = 0; rg < 2; ++rg)
#pragma unroll
    for (int nt = 0; nt < 4; ++nt) of[rg][nt] = (f32x4){0.f, 0.f, 0.f, 0.f};
  float l_acc[2][4] = {{0.f, 0.f, 0.f, 0.f}, {0.f, 0.f, 0.f, 0.f}};

  const int hs = t >> 8;
  const int tt = t & 255;
  const int kr = tt >> 2, kc0 = (tt & 3) * 16;

  // Vt row for this thread: d = kr; k runs along columns (contiguous)
  const short* VtRow = (const short*)Vt_g + (size_t)(bh * 64 + kr) * 2048;

  bf16x8 kv0, kv1, vv0, vv1;
  int mv = 1;
  {
    const int keyRow = (hs * 16 + 0) * 64;
    const short* kg = (const short*)Km +
        (size_t)(b * SEQ + keyRow + kr) * D_MODEL + h * D_K + kc0;
    kv0 = *(const bf16x8*)kg;
    kv1 = *(const bf16x8*)(kg + 8);
    const short* vg = VtRow + keyRow + kc0;
    vv0 = *(const bf16x8*)vg;
    vv1 = *(const bf16x8*)(vg + 8);
    if (tt < 64) mv = mask[b * SEQ + keyRow + tt];
  }

  for (int kt = 0; kt < 16; ++kt) {
    *(bf16x8*)&ks[hs][kr][kc0] = kv0;
    *(bf16x8*)&ks[hs][kr][kc0 + 8] = kv1;
    *(bf16x8*)&vt[hs][kr][kc0] = vv0;
    *(bf16x8*)&vt[hs][kr][kc0 + 8] = vv1;
    if (tt < 64) mk[hs][tt] = mv;

    if (kt + 1 < 16) {
      const int keyRow = (hs * 16 + kt + 1) * 64;
      const short* kg = (const short*)Km +
          (size_t)(b * SEQ + keyRow + kr) * D_MODEL + h * D_K + kc0;
      kv0 = *(const bf16x8*)kg;
      kv1 = *(const bf16x8*)(kg + 8);
      const short* vg = VtRow + keyRow + kc0;
      vv0 = *(const bf16x8*)vg;
      vv1 = *(const bf16x8*)(vg + 8);
      if (tt < 64) mv = mask[b * SEQ + keyRow + tt];
    }
    __syncthreads();

    f32x4 sf[2][4];
#pragma unroll
    for (int nt = 0; nt < 4; ++nt) {
      const bf16x8 kf0 = *(const bf16x8*)&ks[half][l15 + 16 * nt][quad * 8];
      const bf16x8 kf1 =
          *(const bf16x8*)&ks[half][l15 + 16 * nt][quad * 8 + 32];
#pragma unroll
      for (int rg = 0; rg < 2; ++rg) {
        f32x4 acc = (f32x4){0.f, 0.f, 0.f, 0.f};
        acc = __builtin_amdgcn_mfma_f32_16x16x32_bf16(qf[rg][0], kf0, acc, 0, 0, 0);
        acc = __builtin_amdgcn_mfma_f32_16x16x32_bf16(qf[rg][1], kf1, acc, 0, 0, 0);
        sf[rg][nt] = acc;
      }
    }

#pragma unroll
    for (int nt = 0; nt < 4; ++nt) {
      const bool dead = (mk[half][l15 + 16 * nt] == 0);
#pragma unroll
      for (int rg = 0; rg < 2; ++rg)
#pragma unroll
        for (int r = 0; r < 4; ++r) {
          float p = __expf(fmaf(sf[rg][nt][r], 0.125f, -8.f));
          if (dead) p = 0.f;
          l_acc[rg][r] += p;
          pb[wave][rg * 16 + quad * 4 + r][l15 + 16 * nt] = (short)f2b(p);
        }
    }

#pragma unroll
    for (int kc = 0; kc < 2; ++kc) {
      bf16x8 pf[2];
#pragma unroll
      for (int rg = 0; rg < 2; ++rg)
        pf[rg] = *(const bf16x8*)&pb[wave][rg * 16 + l15][kc * 32 + quad * 8];
#pragma unroll
      for (int nt = 0; nt < 4; ++nt) {
        const bf16x8 vf =
            *(const bf16x8*)&vt[half][l15 + 16 * nt][kc * 32 + quad * 8];
#pragma unroll
        for (int rg = 0; rg < 2; ++rg)
          of[rg][nt] = __builtin_amdgcn_mfma_f32_16x16x32_bf16(
              pf[rg], vf, of[rg][nt], 0, 0, 0);
      }
    }
    __syncthreads();
  }

#pragma unroll
  for (int xm = 1; xm < 16; xm <<= 1)
#pragma unroll
    for (int rg = 0; rg < 2; ++rg)
#pragma unroll
      for (int r = 0; r < 4; ++r)
        l_acc[rg][r] += __shfl_xor(l_acc[rg][r], xm, 64);

#pragma unroll
  for (int rg = 0; rg < 2; ++rg)
#pragma unroll
    for (int nt = 0; nt < 4; ++nt)
#pragma unroll
      for (int r = 0; r < 4; ++r)
        mg[wave][rg * 16 + quad * 4 + r][l15 + 16 * nt] = of[rg][nt][r];
  if (l15 == 0) {
#pragma unroll
    for (int rg = 0; rg < 2; ++rg)
#pragma unroll
      for (int r = 0; r < 4; ++r)
        mg[wave][rg * 16 + quad * 4 + r][64] = l_acc[rg][r];
  }
  __syncthreads();

  if (wave < 4) {
    const int pw = wave + 4;
#pragma unroll
    for (int rg = 0; rg < 2; ++rg)
#pragma unroll
      for (int r = 0; r < 4; ++r) {
        const int qrow = rg * 16 + quad * 4 + r;
        const float inv = 1.f / (l_acc[rg][r] + mg[pw][qrow][64]);
        const int row = qt * 128 + wave * 32 + qrow;
        bf16* cp = ctx + (size_t)(b * SEQ + row) * D_MODEL + h * D_K;
#pragma unroll
        for (int nt = 0; nt < 4; ++nt)
          cp[l15 + 16 * nt] = __float2bfloat16(
              (of[rg][nt][r] + mg[pw][qrow][l15 + 16 * nt]) * inv);
      }
  }
}

// ---------------------------------------------------------------------------
// Wave-per-row LayerNorm (single input): out = LN(base)*g+beta.
// block 256 = 4 rows, grid NROWS/4. Shfl butterfly only.
// ---------------------------------------------------------------------------
template <typename BT, typename OT>
__global__ __launch_bounds__(256) void ln_kernel(
    const BT* __restrict__ base, const float* __restrict__ g,
    const float* __restrict__ beta, OT* __restrict__ out) {
  const int wave = threadIdx.x >> 6;
  const int lane = threadIdx.x & 63;
  const int row = blockIdx.x * 4 + wave;
  const size_t rb = (size_t)row * D_MODEL + lane * 8;

  float v[8];
  ld8f(base + rb, v);

  float s = 0.f;
#pragma unroll
  for (int i = 0; i < 8; ++i) s += v[i];
#pragma unroll
  for (int xm = 1; xm < 64; xm <<= 1) s += __shfl_xor(s, xm, 64);
  const float mu = s * (1.f / (float)D_MODEL);

  float q = 0.f;
#pragma unroll
  for (int i = 0; i < 8; ++i) {
    v[i] -= mu;
    q += v[i] * v[i];
  }
#pragma unroll
  for (int xm = 1; xm < 64; xm <<= 1) q += __shfl_xor(q, xm, 64);
  const float rs = rsqrtf(q * (1.f / (float)D_MODEL) + 1e-5f);

  float gv[8], bv[8];
  ld8f(g + lane * 8, gv);
  ld8f(beta + lane * 8, bv);
#pragma unroll
  for (int i = 0; i < 8; ++i) v[i] = v[i] * rs * gv[i] + bv[i];
  st8f(out + rb, v);
}

// ---------------------------------------------------------------------------
extern "C" void kernel_launch(void* const* d_in, const int* in_sizes, int n_in,
                              void* d_out, int out_size, void* d_ws, size_t ws_size,
                              hipStream_t stream) {
  const float* x     = (const float*)d_in[0];
  const int*   mask  = (const int*)d_in[1];
  const float* Wq    = (const float*)d_in[2];
  const float* bq    = (const float*)d_in[3];
  const float* Wk    = (const float*)d_in[4];
  const float* bk    = (const float*)d_in[5];
  const float* Wv    = (const float*)d_in[6];
  const float* bv    = (const float*)d_in[7];
  const float* Wo    = (const float*)d_in[8];
  const float* bo    = (const float*)d_in[9];
  const float* W1    = (const float*)d_in[10];
  const float* b1    = (const float*)d_in[11];
  const float* W2    = (const float*)d_in[12];
  const float* b2    = (const float*)d_in[13];
  const float* g1    = (const float*)d_in[14];
  const float* beta1 = (const float*)d_in[15];
  const float* g2    = (const float*)d_in[16];
  const float* beta2 = (const float*)d_in[17];
  float* out = (float*)d_out;

  char* ws = (char*)d_ws;
  const size_t MB4 = (size_t)NROWS * D_MODEL * sizeof(bf16);  // 4 MiB
  bf16* q        = (bf16*)(ws + 0 * MB4);
  bf16* kbuf     = (bf16*)(ws + 1 * MB4);
  bf16* vbuf     = (bf16*)(ws + 2 * MB4);  // ffacc later
  bf16* ctx      = (bf16*)(ws + 3 * MB4);
  bf16* xb       = (bf16*)(ws + 4 * MB4);  // [16,20), dead after Wo
  bf16* vtbuf    = (bf16*)(ws + 5 * MB4);  // [20,24), Vt; dead after attn
  bf16* attn_out = q;                      // q dead after attention
  bf16* x1       = kbuf;                   // k dead after attention
  bf16* ffacc    = vbuf;                   // v dead after attention
  bf16* ffmid    = (bf16*)(ws + 4 * MB4);  // [16,32), xb/Vt dead by FF1

  bf16* wt = (bf16*)d_out;  // 6MB transposed bf16 weights (LN2 overwrites)

  const dim3 blk(256);

  // prep: weights -> bf16 transposed; x -> bf16 (z=6)
  prep_kernel<<<dim3(32, 32, 7), blk, 0, stream>>>(Wq, Wk, Wv, Wo, W1, W2, wt,
                                                   x, xb);

  // QKV fused, 64x128 tile: 768 blocks = 3/CU. z=2 (V) writes transposed.
  gemm_bf16_kernel<64, 128, false, false, true>
      <<<dim3(D_MODEL / 128, NROWS / 64, 3), blk, 0, stream>>>(
          xb, D_MODEL, wt + WT_Q, wt + WT_K, wt + WT_V, D_MODEL,
          bq, bk, bv, q, kbuf, vtbuf, D_MODEL, D_MODEL, nullptr);

  // attention (RG=2: 128 q rows per block; V pre-transposed)
  attn_mfma_kernel<<<dim3(SEQ / 128, BATCH * N_HEADS), dim3(512), 0, stream>>>(
      q, kbuf, vtbuf, mask, ctx);

  // Wo projection + residual (xb), 64x64 tile: 512 blocks = 2/CU
  gemm_bf16_kernel<64, 64, false, true, false>
      <<<dim3(D_MODEL / 64, NROWS / 64, 1), blk, 0, stream>>>(
          ctx, D_MODEL, wt + WT_O, wt + WT_O, wt + WT_O, D_MODEL,
          bo, bo, bo, attn_out, attn_out, attn_out, D_MODEL, D_MODEL, xb);

  // LN1: x1 = LN(attn_out) -> bf16
  ln_kernel<bf16, bf16><<<NROWS / 4, blk, 0, stream>>>(attn_out, g1, beta1, x1);

  // FF1, 64x128 tile: ffmid = relu(x1 @ W1 + b1), 1024 blocks = 4/CU
  gemm_bf16_kernel<64, 128, true, false, false>
      <<<dim3(D_FF / 128, NROWS / 64, 1), blk, 0, stream>>>(
          x1, D_MODEL, wt + WT_1, wt + WT_1, wt + WT_1, D_MODEL,
          b1, b1, b1, ffmid, ffmid, ffmid, D_FF, D_MODEL, nullptr);

  // FF2 (K=2048) + residual (x1), 64x64 tile: 512 blocks = 2/CU
  gemm_bf16_kernel<64, 64, false, true, false>
      <<<dim3(D_MODEL / 64, NROWS / 64, 1), blk, 0, stream>>>(
          ffmid, D_FF, wt + WT_2, wt + WT_2, wt + WT_2, D_FF,
          b2, b2, b2, ffacc, ffacc, ffacc, D_MODEL, D_FF, x1);

  // LN2 -> fp32 output (overwrites wt scratch)
  ln_kernel<bf16, float><<<NROWS / 4, blk, 0, stream>>>(ffacc, g2, beta2, out);
}

// Round 14
// 198.849 us; speedup vs baseline: 1.0743x; 1.0082x over previous
//
#include <hip/hip_runtime.h>
#include <hip/hip_bf16.h>

// EncoderLayer: B=2, S=2048, D_MODEL=512, H=8, D_FF=2048
// Round 28: r27 confirmed r25 best (200.5 ~ 199.9). Last measured attn
// defect: pb softmax scatter = 32 scalar LDS stores/thread/iter (largest
// remaining LDS stream; same defect class as the V-scatter r20 removed).
// Fix: SWAP QK^T operands (mfma(kf,qf)) -> S fragment transposed (m89:
// col=lane): thread holds 4 CONSECUTIVE keys (quad*4+r) at fixed qrow
// (rg*16+l15) -> pb store = 8 x bf16x4 (8B) into the SAME [qrow][key]
// layout; PV pf read byte-identical. Mask: 4 x int4 reads. l_acc
// reduction: 32 shfl -> 4 (xm=16,32); both halves' sums merged via mg.
// LDS instr/thread/iter ~61 -> ~37. pb stride stays 72 (16B rows, r26
// lesson). Everything else byte-identical to r25/r27.
// ws (MiB): q[0,4)->attn_out; k[4,8)->x1; v[8,12)->ffacc; ctx[12,16);
//   xb[16,20) (dead after Wo); Vt[20,24) (dead after attn);
//   ffmid[16,32) after LN1. Peak 32 MiB.
// d_out first 6MB = transposed bf16 weights (LN2 overwrites at end).

#define D_MODEL 512
#define N_HEADS 8
#define D_K 64
#define D_FF 2048
#define BATCH 2
#define SEQ 2048
#define NROWS (BATCH * SEQ)

typedef __hip_bfloat16 bf16;
typedef __attribute__((ext_vector_type(8))) short bf16x8;
typedef __attribute__((ext_vector_type(4))) short bf16x4;
typedef __attribute__((ext_vector_type(4))) float f32x4;

__device__ __forceinline__ unsigned short f2b(float f) {
  union { bf16 b; unsigned short u; } cv;
  cv.b = __float2bfloat16(f);
  return cv.u;
}
__device__ __forceinline__ float b2f(unsigned short u) {
  return __uint_as_float(((unsigned int)u) << 16);
}
__device__ __forceinline__ float toF(const bf16 x) { return __bfloat162float(x); }
__device__ __forceinline__ float toF(const float x) { return x; }
__device__ __forceinline__ void storeC(float* p, float v) { *p = v; }
__device__ __forceinline__ void storeC(bf16* p, float v) {
  *p = __float2bfloat16(v);
}

__device__ __forceinline__ void ld8f(const float* p, float* v) {
  const float4 a = *(const float4*)p;
  const float4 b = *(const float4*)(p + 4);
  v[0] = a.x; v[1] = a.y; v[2] = a.z; v[3] = a.w;
  v[4] = b.x; v[5] = b.y; v[6] = b.z; v[7] = b.w;
}
__device__ __forceinline__ void ld8f(const bf16* p, float* v) {
  const bf16x8 u = *(const bf16x8*)p;
#pragma unroll
  for (int i = 0; i < 8; ++i) v[i] = b2f((unsigned short)u[i]);
}
__device__ __forceinline__ void st8f(float* p, const float* v) {
  *(float4*)p = make_float4(v[0], v[1], v[2], v[3]);
  *(float4*)(p + 4) = make_float4(v[4], v[5], v[6], v[7]);
}
__device__ __forceinline__ void st8f(bf16* p, const float* v) {
  bf16x8 u;
#pragma unroll
  for (int i = 0; i < 8; ++i) u[i] = (short)f2b(v[i]);
  *(bf16x8*)p = u;
}

// Wt element offsets inside the d_out scratch region
#define WT_Q 0
#define WT_K 262144
#define WT_V 524288
#define WT_O 786432
#define WT_1 1048576
#define WT_2 2097152

// ---------------------------------------------------------------------------
// prep: z<6: W[R][Cn] fp32 -> Wt[Cn][R] bf16 (transposed). z=6: x -> bf16.
// ---------------------------------------------------------------------------
__global__ __launch_bounds__(256) void prep_kernel(
    const float* __restrict__ Wq, const float* __restrict__ Wk,
    const float* __restrict__ Wv, const float* __restrict__ Wo,
    const float* __restrict__ W1, const float* __restrict__ W2,
    bf16* __restrict__ outw, const float* __restrict__ x,
    bf16* __restrict__ xb) {
  const int z = blockIdx.z;
  const int t = threadIdx.x;

  if (z == 6) {  // xconv
    const size_t base =
        ((size_t)(blockIdx.y * 32 + blockIdx.x) * 2048) + (size_t)t * 8;
    float v[8];
    ld8f(x + base, v);
    st8f(xb + base, v);
    return;
  }

  const float* W;
  int R, Cn;
  size_t off;
  if (z == 0)      { W = Wq; R = 512;  Cn = 512;  off = WT_Q; }
  else if (z == 1) { W = Wk; R = 512;  Cn = 512;  off = WT_K; }
  else if (z == 2) { W = Wv; R = 512;  Cn = 512;  off = WT_V; }
  else if (z == 3) { W = Wo; R = 512;  Cn = 512;  off = WT_O; }
  else if (z == 4) { W = W1; R = 512;  Cn = 2048; off = WT_1; }
  else             { W = W2; R = 2048; Cn = 512;  off = WT_2; }
  const int c0 = blockIdx.x * 64;
  const int r0 = blockIdx.y * 64;
  if (c0 >= Cn || r0 >= R) return;

  __shared__ short tile[64][72];  // [c][r]
  {
    const int r = t >> 2, cg = (t & 3) * 16;
    const float* src = &W[(size_t)(r0 + r) * Cn + c0 + cg];
#pragma unroll
    for (int i = 0; i < 4; ++i) {
      const float4 v = *(const float4*)(src + 4 * i);
      tile[cg + 4 * i + 0][r] = (short)f2b(v.x);
      tile[cg + 4 * i + 1][r] = (short)f2b(v.y);
      tile[cg + 4 * i + 2][r] = (short)f2b(v.z);
      tile[cg + 4 * i + 3][r] = (short)f2b(v.w);
    }
  }
  __syncthreads();
  {
    const int c = t >> 2, rg = (t & 3) * 16;
    short* dst = (short*)outw + off + (size_t)(c0 + c) * R + r0 + rg;
    *(bf16x8*)dst = *(const bf16x8*)&tile[c][rg];
    *(bf16x8*)(dst + 8) = *(const bf16x8*)&tile[c][rg + 8];
  }
}

// ---------------------------------------------------------------------------
// gemm_bf16<BM,BN,RELU,RESID,TRV>: C = A @ Wt^T + bias (+ R resid, ReLU).
// A[row][k] bf16 (lda), Wt[n][k] bf16 (ldk). BK=64, block=256 (4 waves).
// r20 register-prefetch staging; r25: linear [.][64] LDS with both-sides
// XOR swizzle col^=(row&7)*8 (shorts) on ds_write commits and b128 frag
// reads -> all accesses at the b128 bank floor. TRV: blockIdx.z==2 writes
// C transposed into Vt[(b*8+h)*64+d][k]. Grid (Nview/BN, M/BM, NZ).
// ---------------------------------------------------------------------------
template <int BM, int BN, bool RELU, bool RESID, bool TRV>
__global__ __launch_bounds__(256) void gemm_bf16_kernel(
    const bf16* __restrict__ A, int lda,
    const bf16* __restrict__ Wt0, const bf16* __restrict__ Wt1,
    const bf16* __restrict__ Wt2, int ldk,
    const float* __restrict__ b0, const float* __restrict__ b1,
    const float* __restrict__ b2,
    bf16* __restrict__ C0, bf16* __restrict__ C1, bf16* __restrict__ C2,
    int ldc, int K, const bf16* __restrict__ R) {
  const bf16* Wt = (blockIdx.z == 0) ? Wt0 : (blockIdx.z == 1 ? Wt1 : Wt2);
  const float* bias = (blockIdx.z == 0) ? b0 : (blockIdx.z == 1 ? b1 : b2);
  bf16* C = (blockIdx.z == 0) ? C0 : (blockIdx.z == 1 ? C1 : C2);

  constexpr int WX = BN / 64;        // waves along N
  constexpr int WY = 4 / WX;         // waves along M
  constexpr int RG = BM / (16 * WY); // 16-row groups per wave
  constexpr int NA = BM / 32;        // A 16B-slots per thread
  constexpr int NW = BN / 32;        // W 16B-slots per thread

  __shared__ __align__(16) short as_[BM][64];
  __shared__ __align__(16) short bs[BN][64];

  const int rowBase = blockIdx.y * BM;
  const int colBase = blockIdx.x * BN;
  const int t = threadIdx.x;
  const int wave = t >> 6;
  const int lane = t & 63;
  const int quad = lane >> 4;
  const int l15 = lane & 15;
  const int wy = wave / WX;
  const int wx = wave % WX;

  const int arow = (NA == 2) ? (t >> 2) : (t >> 1);
  const int akc = (NA == 2) ? ((t & 3) * 16) : ((t & 1) * 32);
  const int wrow = (NW == 2) ? (t >> 2) : (t >> 1);
  const int wkc = (NW == 2) ? ((t & 3) * 16) : ((t & 1) * 32);

  const short* Abase = (const short*)A + (size_t)(rowBase + arow) * lda + akc;
  const short* Wbase = (const short*)Wt + (size_t)(colBase + wrow) * ldk + wkc;

  bf16x8 areg[NA], wreg[NW];
#pragma unroll
  for (int i = 0; i < NA; ++i) areg[i] = *(const bf16x8*)(Abase + 8 * i);
#pragma unroll
  for (int i = 0; i < NW; ++i) wreg[i] = *(const bf16x8*)(Wbase + 8 * i);

  f32x4 acc[RG][4];
#pragma unroll
  for (int i = 0; i < RG; ++i)
#pragma unroll
    for (int nt = 0; nt < 4; ++nt) acc[i][nt] = (f32x4){0.f, 0.f, 0.f, 0.f};

  const int aswz = (arow & 7) * 8;
  const int wswz = (wrow & 7) * 8;
  const int rswz = (l15 & 7) * 8;

  for (int k0 = 0; k0 < K; k0 += 64) {
    // commit prefetched tile (swizzled cols)
#pragma unroll
    for (int i = 0; i < NA; ++i)
      *(bf16x8*)&as_[arow][(akc + 8 * i) ^ aswz] = areg[i];
#pragma unroll
    for (int i = 0; i < NW; ++i)
      *(bf16x8*)&bs[wrow][(wkc + 8 * i) ^ wswz] = wreg[i];

    // issue next tile's loads
    if (k0 + 64 < K) {
#pragma unroll
      for (int i = 0; i < NA; ++i)
        areg[i] = *(const bf16x8*)(Abase + k0 + 64 + 8 * i);
#pragma unroll
      for (int i = 0; i < NW; ++i)
        wreg[i] = *(const bf16x8*)(Wbase + k0 + 64 + 8 * i);
    }
    __syncthreads();

#pragma unroll
    for (int kc = 0; kc < 2; ++kc) {
      bf16x8 af[RG];
#pragma unroll
      for (int i = 0; i < RG; ++i)
        af[i] = *(const bf16x8*)
            &as_[wy * (16 * RG) + i * 16 + l15][(quad * 8 + kc * 32) ^ rswz];
#pragma unroll
      for (int nt = 0; nt < 4; ++nt) {
        const bf16x8 bfr = *(const bf16x8*)
            &bs[wx * 64 + nt * 16 + l15][(quad * 8 + kc * 32) ^ rswz];
#pragma unroll
        for (int i = 0; i < RG; ++i)
          acc[i][nt] = __builtin_amdgcn_mfma_f32_16x16x32_bf16(
              af[i], bfr, acc[i][nt], 0, 0, 0);
      }
    }
    __syncthreads();
  }

  if (TRV && blockIdx.z == 2) {
    // transposed V write: Vt[(b*8+h)*64 + d][k], 4 bf16 (8B) per store
#pragma unroll
    for (int i = 0; i < RG; ++i)
#pragma unroll
      for (int nt = 0; nt < 4; ++nt) {
        const int col = colBase + wx * 64 + nt * 16 + l15;
        const int h_ = col >> 6, d_ = col & 63;
        const int row0 = rowBase + wy * (16 * RG) + i * 16 + quad * 4;
        const int b_ = row0 >> 11, k0_ = row0 & 2047;
        const float bia = bias[col];
        bf16x4 u;
#pragma unroll
        for (int r = 0; r < 4; ++r) u[r] = (short)f2b(acc[i][nt][r] + bia);
        *(bf16x4*)((unsigned short*)C +
                   ((size_t)((b_ * 8 + h_) * 64 + d_)) * 2048 + k0_) = u;
      }
    return;
  }

#pragma unroll
  for (int i = 0; i < RG; ++i)
#pragma unroll
    for (int nt = 0; nt < 4; ++nt) {
      const int col = colBase + wx * 64 + nt * 16 + l15;
#pragma unroll
      for (int r = 0; r < 4; ++r) {
        const int row = rowBase + wy * (16 * RG) + i * 16 + quad * 4 + r;
        float v = acc[i][nt][r] + bias[col];
        if (RESID) v += toF(R[(size_t)row * ldc + col]);
        if (RELU) v = fmaxf(v, 0.f);
        storeC(&C[(size_t)row * ldc + col], v);
      }
    }
}

// ---------------------------------------------------------------------------
// MFMA flash attention, RG=2. grid (SEQ/128, B*H), block 512.
// V pre-transposed (Vt[(b*8+h)*64+d][k]) -> V staging = 2 b128 writes.
// r28: swapped QK^T (mfma(kf,qf)) -> S fragment transposed: thread holds
// keys quad*4+r (consecutive) at qrow rg*16+l15 -> pb stores = 8 x bf16x4
// (was 32 scalar); mask = 4 x int4 reads; l_acc reduce = 4 shfl (xm=16,32);
// both halves' sums merged via mg[.][64]. PV reads byte-identical.
// ---------------------------------------------------------------------------
__global__ __launch_bounds__(512) void attn_mfma_kernel(
    const bf16* __restrict__ Q, const bf16* __restrict__ Km,
    const bf16* __restrict__ Vt_g, const int* __restrict__ mask,
    bf16* __restrict__ ctx) {
  const int qt = blockIdx.x;
  const int bh = blockIdx.y;
  const int b = bh >> 3;
  const int h = bh & 7;
  const int t = threadIdx.x;
  const int wave = t >> 6;
  const int half = wave >> 2;
  const int wq = wave & 3;
  const int lane = t & 63;
  const int quad = lane >> 4;
  const int l15 = lane & 15;

  __shared__ __align__(16) char smem[74240];
  auto ks = (short(*)[64][72])(smem);
  auto vt = (short(*)[64][72])(smem + 18432);
  auto pb = (short(*)[32][72])(smem + 36864);
  auto mk = (int(*)[64])(smem + 73728);
  auto mg = (float(*)[32][68])(smem);  // aliases ks/vt/pb after final barrier

  bf16x8 qf[2][2];
#pragma unroll
  for (int rg = 0; rg < 2; ++rg) {
    const short* qg = (const short*)Q +
        (size_t)(b * SEQ + qt * 128 + wq * 32 + rg * 16 + l15) * D_MODEL +
        h * D_K + quad * 8;
    qf[rg][0] = *(const bf16x8*)qg;
    qf[rg][1] = *(const bf16x8*)(qg + 32);
  }

  f32x4 of[2][4];
#pragma unroll
  for (int rg = 0; rg < 2; ++rg)
#pragma unroll
    for (int nt = 0; nt < 4; ++nt) of[rg][nt] = (f32x4){0.f, 0.f, 0.f, 0.f};
  // l_acc[rg]: partial softmax denom for qrow = rg*16 + l15 (this half)
  float l_acc[2] = {0.f, 0.f};

  const int hs = t >> 8;
  const int tt = t & 255;
  const int kr = tt >> 2, kc0 = (tt & 3) * 16;

  // Vt row for this thread: d = kr; k runs along columns (contiguous)
  const short* VtRow = (const short*)Vt_g + (size_t)(bh * 64 + kr) * 2048;

  bf16x8 kv0, kv1, vv0, vv1;
  int mv = 1;
  {
    const int keyRow = (hs * 16 + 0) * 64;
    const short* kg = (const short*)Km +
        (size_t)(b * SEQ + keyRow + kr) * D_MODEL + h * D_K + kc0;
    kv0 = *(const bf16x8*)kg;
    kv1 = *(const bf16x8*)(kg + 8);
    const short* vg = VtRow + keyRow + kc0;
    vv0 = *(const bf16x8*)vg;
    vv1 = *(const bf16x8*)(vg + 8);
    if (tt < 64) mv = mask[b * SEQ + keyRow + tt];
  }

  for (int kt = 0; kt < 16; ++kt) {
    *(bf16x8*)&ks[hs][kr][kc0] = kv0;
    *(bf16x8*)&ks[hs][kr][kc0 + 8] = kv1;
    *(bf16x8*)&vt[hs][kr][kc0] = vv0;
    *(bf16x8*)&vt[hs][kr][kc0 + 8] = vv1;
    if (tt < 64) mk[hs][tt] = mv;

    if (kt + 1 < 16) {
      const int keyRow = (hs * 16 + kt + 1) * 64;
      const short* kg = (const short*)Km +
          (size_t)(b * SEQ + keyRow + kr) * D_MODEL + h * D_K + kc0;
      kv0 = *(const bf16x8*)kg;
      kv1 = *(const bf16x8*)(kg + 8);
      const short* vg = VtRow + keyRow + kc0;
      vv0 = *(const bf16x8*)vg;
      vv1 = *(const bf16x8*)(vg + 8);
      if (tt < 64) mv = mask[b * SEQ + keyRow + tt];
    }
    __syncthreads();

    // S^T fragments: sf[nt][rg] has key = nt*16 + quad*4 + r (rows),
    // qrow = rg*16 + l15 (cols) -- operands SWAPPED vs classic.
    f32x4 sf[4][2];
#pragma unroll
    for (int nt = 0; nt < 4; ++nt) {
      const bf16x8 kf0 = *(const bf16x8*)&ks[half][l15 + 16 * nt][quad * 8];
      const bf16x8 kf1 =
          *(const bf16x8*)&ks[half][l15 + 16 * nt][quad * 8 + 32];
#pragma unroll
      for (int rg = 0; rg < 2; ++rg) {
        f32x4 acc = (f32x4){0.f, 0.f, 0.f, 0.f};
        acc = __builtin_amdgcn_mfma_f32_16x16x32_bf16(kf0, qf[rg][0], acc, 0, 0, 0);
        acc = __builtin_amdgcn_mfma_f32_16x16x32_bf16(kf1, qf[rg][1], acc, 0, 0, 0);
        sf[nt][rg] = acc;
      }
    }

#pragma unroll
    for (int nt = 0; nt < 4; ++nt) {
      const int4 mv4 = *(const int4*)&mk[half][nt * 16 + quad * 4];
#pragma unroll
      for (int rg = 0; rg < 2; ++rg) {
        bf16x4 u;
#pragma unroll
        for (int r = 0; r < 4; ++r) {
          float p = __expf(fmaf(sf[nt][rg][r], 0.125f, -8.f));
          const int mr = (r == 0) ? mv4.x : (r == 1) ? mv4.y
                          : (r == 2) ? mv4.z : mv4.w;
          if (mr == 0) p = 0.f;
          l_acc[rg] += p;
          u[r] = (short)f2b(p);
        }
        *(bf16x4*)&pb[wave][rg * 16 + l15][nt * 16 + quad * 4] = u;
      }
    }

#pragma unroll
    for (int kc = 0; kc < 2; ++kc) {
      bf16x8 pf[2];
#pragma unroll
      for (int rg = 0; rg < 2; ++rg)
        pf[rg] = *(const bf16x8*)&pb[wave][rg * 16 + l15][kc * 32 + quad * 8];
#pragma unroll
      for (int nt = 0; nt < 4; ++nt) {
        const bf16x8 vf =
            *(const bf16x8*)&vt[half][l15 + 16 * nt][kc * 32 + quad * 8];
#pragma unroll
        for (int rg = 0; rg < 2; ++rg)
          of[rg][nt] = __builtin_amdgcn_mfma_f32_16x16x32_bf16(
              pf[rg], vf, of[rg][nt], 0, 0, 0);
      }
    }
    __syncthreads();
  }

  // reduce l_acc over quads (lanes sharing l15 hold same qrow)
#pragma unroll
  for (int xm = 16; xm < 64; xm <<= 1)
#pragma unroll
    for (int rg = 0; rg < 2; ++rg)
      l_acc[rg] += __shfl_xor(l_acc[rg], xm, 64);

#pragma unroll
  for (int rg = 0; rg < 2; ++rg)
#pragma unroll
    for (int nt = 0; nt < 4; ++nt)
#pragma unroll
      for (int r = 0; r < 4; ++r)
        mg[wave][rg * 16 + quad * 4 + r][l15 + 16 * nt] = of[rg][nt][r];
  if (quad == 0) {
#pragma unroll
    for (int rg = 0; rg < 2; ++rg)
      mg[wave][rg * 16 + l15][64] = l_acc[rg];
  }
  __syncthreads();

  if (wave < 4) {
    const int pw = wave + 4;
#pragma unroll
    for (int rg = 0; rg < 2; ++rg)
#pragma unroll
      for (int r = 0; r < 4; ++r) {
        const int qrow = rg * 16 + quad * 4 + r;
        const float inv =
            1.f / (mg[wave][qrow][64] + mg[pw][qrow][64]);
        const int row = qt * 128 + wave * 32 + qrow;
        bf16* cp = ctx + (size_t)(b * SEQ + row) * D_MODEL + h * D_K;
#pragma unroll
        for (int nt = 0; nt < 4; ++nt)
          cp[l15 + 16 * nt] = __float2bfloat16(
              (of[rg][nt][r] + mg[pw][qrow][l15 + 16 * nt]) * inv);
      }
  }
}

// ---------------------------------------------------------------------------
// Wave-per-row LayerNorm (single input): out = LN(base)*g+beta.
// block 256 = 4 rows, grid NROWS/4. Shfl butterfly only.
// ---------------------------------------------------------------------------
template <typename BT, typename OT>
__global__ __launch_bounds__(256) void ln_kernel(
    const BT* __restrict__ base, const float* __restrict__ g,
    const float* __restrict__ beta, OT* __restrict__ out) {
  const int wave = threadIdx.x >> 6;
  const int lane = threadIdx.x & 63;
  const int row = blockIdx.x * 4 + wave;
  const size_t rb = (size_t)row * D_MODEL + lane * 8;

  float v[8];
  ld8f(base + rb, v);

  float s = 0.f;
#pragma unroll
  for (int i = 0; i < 8; ++i) s += v[i];
#pragma unroll
  for (int xm = 1; xm < 64; xm <<= 1) s += __shfl_xor(s, xm, 64);
  const float mu = s * (1.f / (float)D_MODEL);

  float q = 0.f;
#pragma unroll
  for (int i = 0; i < 8; ++i) {
    v[i] -= mu;
    q += v[i] * v[i];
  }
#pragma unroll
  for (int xm = 1; xm < 64; xm <<= 1) q += __shfl_xor(q, xm, 64);
  const float rs = rsqrtf(q * (1.f / (float)D_MODEL) + 1e-5f);

  float gv[8], bv[8];
  ld8f(g + lane * 8, gv);
  ld8f(beta + lane * 8, bv);
#pragma unroll
  for (int i = 0; i < 8; ++i) v[i] = v[i] * rs * gv[i] + bv[i];
  st8f(out + rb, v);
}

// ---------------------------------------------------------------------------
extern "C" void kernel_launch(void* const* d_in, const int* in_sizes, int n_in,
                              void* d_out, int out_size, void* d_ws, size_t ws_size,
                              hipStream_t stream) {
  const float* x     = (const float*)d_in[0];
  const int*   mask  = (const int*)d_in[1];
  const float* Wq    = (const float*)d_in[2];
  const float* bq    = (const float*)d_in[3];
  const float* Wk    = (const float*)d_in[4];
  const float* bk    = (const float*)d_in[5];
  const float* Wv    = (const float*)d_in[6];
  const float* bv    = (const float*)d_in[7];
  const float* Wo    = (const float*)d_in[8];
  const float* bo    = (const float*)d_in[9];
  const float* W1    = (const float*)d_in[10];
  const float* b1    = (const float*)d_in[11];
  const float* W2    = (const float*)d_in[12];
  const float* b2    = (const float*)d_in[13];
  const float* g1    = (const float*)d_in[14];
  const float* beta1 = (const float*)d_in[15];
  const float* g2    = (const float*)d_in[16];
  const float* beta2 = (const float*)d_in[17];
  float* out = (float*)d_out;

  char* ws = (char*)d_ws;
  const size_t MB4 = (size_t)NROWS * D_MODEL * sizeof(bf16);  // 4 MiB
  bf16* q        = (bf16*)(ws + 0 * MB4);
  bf16* kbuf     = (bf16*)(ws + 1 * MB4);
  bf16* vbuf     = (bf16*)(ws + 2 * MB4);  // ffacc later
  bf16* ctx      = (bf16*)(ws + 3 * MB4);
  bf16* xb       = (bf16*)(ws + 4 * MB4);  // [16,20), dead after Wo
  bf16* vtbuf    = (bf16*)(ws + 5 * MB4);  // [20,24), Vt; dead after attn
  bf16* attn_out = q;                      // q dead after attention
  bf16* x1       = kbuf;                   // k dead after attention
  bf16* ffacc    = vbuf;                   // v dead after attention
  bf16* ffmid    = (bf16*)(ws + 4 * MB4);  // [16,32), xb/Vt dead by FF1

  bf16* wt = (bf16*)d_out;  // 6MB transposed bf16 weights (LN2 overwrites)

  const dim3 blk(256);

  // prep: weights -> bf16 transposed; x -> bf16 (z=6)
  prep_kernel<<<dim3(32, 32, 7), blk, 0, stream>>>(Wq, Wk, Wv, Wo, W1, W2, wt,
                                                   x, xb);

  // QKV fused, 64x128 tile: 768 blocks = 3/CU. z=2 (V) writes transposed.
  gemm_bf16_kernel<64, 128, false, false, true>
      <<<dim3(D_MODEL / 128, NROWS / 64, 3), blk, 0, stream>>>(
          xb, D_MODEL, wt + WT_Q, wt + WT_K, wt + WT_V, D_MODEL,
          bq, bk, bv, q, kbuf, vtbuf, D_MODEL, D_MODEL, nullptr);

  // attention (RG=2: 128 q rows per block; V pre-transposed)
  attn_mfma_kernel<<<dim3(SEQ / 128, BATCH * N_HEADS), dim3(512), 0, stream>>>(
      q, kbuf, vtbuf, mask, ctx);

  // Wo projection + residual (xb), 64x64 tile: 512 blocks = 2/CU
  gemm_bf16_kernel<64, 64, false, true, false>
      <<<dim3(D_MODEL / 64, NROWS / 64, 1), blk, 0, stream>>>(
          ctx, D_MODEL, wt + WT_O, wt + WT_O, wt + WT_O, D_MODEL,
          bo, bo, bo, attn_out, attn_out, attn_out, D_MODEL, D_MODEL, xb);

  // LN1: x1 = LN(attn_out) -> bf16
  ln_kernel<bf16, bf16><<<NROWS / 4, blk, 0, stream>>>(attn_out, g1, beta1, x1);

  // FF1, 64x128 tile: ffmid = relu(x1 @ W1 + b1), 1024 blocks = 4/CU
  gemm_bf16_kernel<64, 128, true, false, false>
      <<<dim3(D_FF / 128, NROWS / 64, 1), blk, 0, stream>>>(
          x1, D_MODEL, wt + WT_1, wt + WT_1, wt + WT_1, D_MODEL,
          b1, b1, b1, ffmid, ffmid, ffmid, D_FF, D_MODEL, nullptr);

  // FF2 (K=2048) + residual (x1), 64x64 tile: 512 blocks = 2/CU
  gemm_bf16_kernel<64, 64, false, true, false>
      <<<dim3(D_MODEL / 64, NROWS / 64, 1), blk, 0, stream>>>(
          ffmid, D_FF, wt + WT_2, wt + WT_2, wt + WT_2, D_FF,
          b2, b2, b2, ffacc, ffacc, ffacc, D_MODEL, D_FF, x1);

  // LN2 -> fp32 output (overwrites wt scratch)
  ln_kernel<bf16, float><<<NROWS / 4, blk, 0, stream>>>(ffacc, g2, beta2, out);
}